// Round 1
// baseline (276.822 us; speedup 1.0000x reference)
//
#include <hip/hip_runtime.h>
#include <hip/hip_bf16.h>

typedef __bf16 bf16_t;
typedef bf16_t bf16x8 __attribute__((ext_vector_type(8)));
typedef float f32x4 __attribute__((ext_vector_type(4)));

#define MFMA(a, b, c) __builtin_amdgcn_mfma_f32_16x16x32_bf16(a, b, c, 0, 0, 0)

constexpr int B = 8, S = 2048, C = 1024, D = 128;
constexpr float C2 = 0.12751744f; // log2(e)/sqrt(128)

// ---------------- K0: Wt[n][c] = W_sel[c][n], bf16 -----------------
__global__ void k_wt(const float* Wq, const float* Wk, const float* Wv, bf16_t* Wt) {
    int n = blockIdx.x; // 0..383
    const float* src = (n < 128) ? (Wq + n) : (n < 256 ? (Wk + (n - 128)) : (Wv + (n - 256)));
    bf16_t* dst = Wt + (size_t)n * C;
    for (int c = threadIdx.x; c < C; c += blockDim.x)
        dst[c] = (bf16_t)src[(size_t)c * D];
}

// ---------------- K1: QKV projection, 1 wave/block, 32 rows x 128 cols ----
__global__ __launch_bounds__(64) void k_qkv(const float* X, const bf16_t* Wt,
                                            bf16_t* Qb, bf16_t* Kb, float* Vf) {
    int mt = blockIdx.x, nt = blockIdx.y; // mt 0..511, nt 0..2
    int lane = threadIdx.x;
    int lr = lane & 15, lg = lane >> 4;
    int rw = mt * 32;
    f32x4 acc[2][8] = {};
    for (int c0 = 0; c0 < C; c0 += 32) {
        bf16x8 xa[2];
#pragma unroll
        for (int mi = 0; mi < 2; ++mi) {
            const float* xp = X + (size_t)(rw + mi * 16 + lr) * C + c0 + lg * 8;
            f32x4 x0 = *(const f32x4*)xp;
            f32x4 x1 = *(const f32x4*)(xp + 4);
            bf16x8 a;
#pragma unroll
            for (int q = 0; q < 4; ++q) { a[q] = (bf16_t)x0[q]; a[4 + q] = (bf16_t)x1[q]; }
            xa[mi] = a;
        }
        const bf16_t* wb = Wt + (size_t)(nt * 128 + lr) * C + c0 + lg * 8;
#pragma unroll
        for (int nf = 0; nf < 8; ++nf) {
            bf16x8 bfr = *(const bf16x8*)(wb + (size_t)nf * 16 * C);
            acc[0][nf] = MFMA(xa[0], bfr, acc[0][nf]);
            acc[1][nf] = MFMA(xa[1], bfr, acc[1][nf]);
        }
    }
#pragma unroll
    for (int mi = 0; mi < 2; ++mi)
#pragma unroll
        for (int nf = 0; nf < 8; ++nf)
#pragma unroll
            for (int r = 0; r < 4; ++r) {
                size_t m = rw + mi * 16 + lg * 4 + r;
                int d = nf * 16 + lr;
                float v = acc[mi][nf][r];
                if (nt == 0)      Qb[m * D + d] = (bf16_t)v;
                else if (nt == 1) Kb[m * D + d] = (bf16_t)v;
                else              Vf[m * D + d] = v;
            }
}

// ---------------- K2: l[j] = sum_i exp2(c*s), then Vt[d][j] = V[j][d]/l[j] --
__global__ __launch_bounds__(64) void k_stats(const bf16_t* Qb, const bf16_t* Kb,
                                              const float* Vf, bf16_t* Vt) {
    int jt = blockIdx.x, b = blockIdx.y; // jt 0..63
    int lane = threadIdx.x;
    int lr = lane & 15, lg = lane >> 4;
    int j0 = jt * 32;
    __shared__ __align__(16) bf16_t vtile[128 * 32];

    bf16x8 kf[2][4];
#pragma unroll
    for (int jh = 0; jh < 2; ++jh) {
        const bf16x8* kp = (const bf16x8*)(Kb + (size_t)(b * S + j0 + jh * 16 + lr) * D + lg * 8);
#pragma unroll
        for (int kk = 0; kk < 4; ++kk) kf[jh][kk] = kp[kk * 4];
    }
    f32x4 ls0 = {}, ls1 = {};
    for (int i0 = 0; i0 < S; i0 += 16) {
        const bf16x8* qp = (const bf16x8*)(Qb + (size_t)(b * S + i0 + lr) * D + lg * 8);
        bf16x8 q0 = qp[0], q1 = qp[4], q2 = qp[8], q3 = qp[12];
        f32x4 s0 = {}, s1 = {};
        s0 = MFMA(q0, kf[0][0], s0); s0 = MFMA(q1, kf[0][1], s0);
        s0 = MFMA(q2, kf[0][2], s0); s0 = MFMA(q3, kf[0][3], s0);
        s1 = MFMA(q0, kf[1][0], s1); s1 = MFMA(q1, kf[1][1], s1);
        s1 = MFMA(q2, kf[1][2], s1); s1 = MFMA(q3, kf[1][3], s1);
#pragma unroll
        for (int r = 0; r < 4; ++r) {
            ls0[r] += exp2f(s0[r] * C2);
            ls1[r] += exp2f(s1[r] * C2);
        }
    }
    float t0 = ls0[0] + ls0[1] + ls0[2] + ls0[3];
    float t1 = ls1[0] + ls1[1] + ls1[2] + ls1[3];
    t0 += __shfl_xor(t0, 16); t0 += __shfl_xor(t0, 32);
    t1 += __shfl_xor(t1, 16); t1 += __shfl_xor(t1, 32);
    float inv0 = 1.0f / t0, inv1 = 1.0f / t1; // for j = j0+lr, j0+16+lr

    // scale + transpose V into Vt
    for (int p = 0; p < 16; ++p) {
        int u = p * 64 + lane;
        int jj = u >> 5, dq = u & 31; // jj 0..31, dq 0..31
        f32x4 v = *(const f32x4*)(Vf + (size_t)(b * S + j0 + jj) * D + dq * 4);
        float ia = __shfl(inv0, jj & 15);
        float ib = __shfl(inv1, jj & 15);
        float inv = (jj < 16) ? ia : ib;
#pragma unroll
        for (int q = 0; q < 4; ++q) {
            int d = dq * 4 + q;
            vtile[d * 32 + (jj ^ ((d & 3) << 3))] = (bf16_t)(v[q] * inv);
        }
    }
    __syncthreads();
    for (int p = 0; p < 8; ++p) {
        int u = p * 64 + lane;
        int d = u >> 2, jg = u & 3;
        int col0 = (jg * 8) ^ ((d & 3) << 3);
        bf16x8 row = *(const bf16x8*)&vtile[d * 32 + col0];
        *(bf16x8*)(Vt + (size_t)(b * D + d) * S + j0 + jg * 8) = row;
    }
}

// ---------------- K3: out[i][d] = sum_j exp2(c*s[i][j]) * Vt[d][j] ---------
__global__ __launch_bounds__(64) void k_out(const bf16_t* Qb, const bf16_t* Kb,
                                            const bf16_t* Vt, float* Out) {
    int it = blockIdx.x, b = blockIdx.y; // it 0..127
    int lane = threadIdx.x;
    int lr = lane & 15, lg = lane >> 4;
    int i16 = it * 16;
    __shared__ __align__(16) bf16_t p_lds[16 * 32];

    const bf16x8* qp = (const bf16x8*)(Qb + (size_t)(b * S + i16 + lr) * D + lg * 8);
    bf16x8 qf0 = qp[0], qf1 = qp[4], qf2 = qp[8], qf3 = qp[12];
    f32x4 acc[8] = {};
    const bf16_t* vb = Vt + (size_t)b * D * S;

    for (int j0 = 0; j0 < S; j0 += 32) {
#pragma unroll
        for (int jh = 0; jh < 2; ++jh) {
            const bf16x8* kp = (const bf16x8*)(Kb + (size_t)(b * S + j0 + jh * 16 + lr) * D + lg * 8);
            f32x4 s = {};
            s = MFMA(qf0, kp[0], s);
            s = MFMA(qf1, kp[4], s);
            s = MFMA(qf2, kp[8], s);
            s = MFMA(qf3, kp[12], s);
#pragma unroll
            for (int r = 0; r < 4; ++r) {
                float pv = exp2f(s[r] * C2);
                int ir = lg * 4 + r;
                int col = jh * 16 + lr;
                p_lds[ir * 32 + (col ^ ((ir & 3) << 3))] = (bf16_t)pv;
            }
        }
        bf16x8 pa = *(const bf16x8*)&p_lds[lr * 32 + ((lg * 8) ^ ((lr & 3) << 3))];
#pragma unroll
        for (int dc = 0; dc < 8; ++dc) {
            const bf16x8* vp = (const bf16x8*)(vb + (size_t)(dc * 16 + lr) * S + j0 + lg * 8);
            acc[dc] = MFMA(pa, vp[0], acc[dc]);
        }
    }
#pragma unroll
    for (int dc = 0; dc < 8; ++dc)
#pragma unroll
        for (int r = 0; r < 4; ++r)
            Out[(size_t)(b * S + i16 + lg * 4 + r) * D + dc * 16 + lr] = acc[dc][r];
}

extern "C" void kernel_launch(void* const* d_in, const int* in_sizes, int n_in,
                              void* d_out, int out_size, void* d_ws, size_t ws_size,
                              hipStream_t stream) {
    const float* X  = (const float*)d_in[0];
    const float* Wq = (const float*)d_in[1];
    const float* Wk = (const float*)d_in[2];
    const float* Wv = (const float*)d_in[3];
    char* ws = (char*)d_ws;
    bf16_t* Wt = (bf16_t*)(ws);                        // 384*1024*2   = 768 KiB
    bf16_t* Qb = (bf16_t*)(ws + (1ull << 20));         // 16384*128*2  = 4 MiB
    bf16_t* Kb = (bf16_t*)(ws + (5ull << 20));         // 4 MiB
    float*  Vf = (float*)(ws + (9ull << 20));          // 16384*128*4  = 8 MiB
    bf16_t* Vt = (bf16_t*)(ws + (17ull << 20));        // 8*128*2048*2 = 4 MiB
    float* Out = (float*)d_out;

    k_wt<<<dim3(384), dim3(256), 0, stream>>>(Wq, Wk, Wv, Wt);
    k_qkv<<<dim3(512, 3), dim3(64), 0, stream>>>(X, Wt, Qb, Kb, Vf);
    k_stats<<<dim3(64, 8), dim3(64), 0, stream>>>(Qb, Kb, Vf, Vt);
    k_out<<<dim3(128, 8), dim3(64), 0, stream>>>(Qb, Kb, Vt, Out);
}

// Round 2
// 141.074 us; speedup vs baseline: 1.9622x; 1.9622x over previous
//
#include <hip/hip_runtime.h>
#include <hip/hip_bf16.h>

typedef __bf16 bf16_t;
typedef bf16_t bf16x8 __attribute__((ext_vector_type(8)));
typedef float f32x4 __attribute__((ext_vector_type(4)));
typedef __attribute__((address_space(1))) const unsigned int gu32_t;
typedef __attribute__((address_space(3))) unsigned int lu32_t;

#define MFMA(a, b, c) __builtin_amdgcn_mfma_f32_16x16x32_bf16(a, b, c, 0, 0, 0)

constexpr int B = 8, S = 2048, C = 1024, D = 128;
constexpr float C2 = 0.12751744f; // log2(e)/sqrt(128)

// ---------------- K0: Wt[n][c] = W_sel[c][n], bf16 -----------------
__global__ void k_wt(const float* Wq, const float* Wk, const float* Wv, bf16_t* Wt) {
    int n = blockIdx.x; // 0..383
    const float* src = (n < 128) ? (Wq + n) : (n < 256 ? (Wk + (n - 128)) : (Wv + (n - 256)));
    bf16_t* dst = Wt + (size_t)n * C;
    for (int c = threadIdx.x; c < C; c += blockDim.x)
        dst[c] = (bf16_t)src[(size_t)c * D];
}

// ---------------- K1: QKV projection, 4 waves, 64x128 tile, dbuf LDS ------
__global__ __launch_bounds__(256) void k_qkv(const float* X, const bf16_t* Wt,
                                             bf16_t* Qb, bf16_t* Kb, float* Vf) {
    __shared__ __align__(16) bf16_t xs[2][64 * 32];   // 8 KiB
    __shared__ __align__(16) bf16_t wt_s[2][128 * 32]; // 16 KiB
    int mt = blockIdx.x, nt = blockIdx.y; // mt 0..255, nt 0..2
    int tid = threadIdx.x;
    int lane = tid & 63, wid = tid >> 6;
    int lr = lane & 15, lg = lane >> 4;
    int wr = wid >> 1, wc = wid & 1; // wave: rows wr*32..+32, cols wc*64..+64
    int rw = mt * 64;
    int xr = tid >> 2, xc = tid & 3;
    const float* xsrc = X + (size_t)(rw + xr) * C + xc * 8;

    f32x4 acc[2][4] = {};

    // prologue: stage k-step 0 into buf 0
    {
        f32x4 x0 = *(const f32x4*)(xsrc);
        f32x4 x1 = *(const f32x4*)(xsrc + 4);
#pragma unroll
        for (int c = 0; c < 2; ++c) {
            const bf16_t* wsrc = Wt + (size_t)(nt * 128 + c * 64 + wid * 16 + (lane >> 2)) * C + (lane & 3) * 8;
            __builtin_amdgcn_global_load_lds((gu32_t*)wsrc, (lu32_t*)&wt_s[0][c * 2048 + wid * 512], 16, 0, 0);
        }
        bf16x8 xv;
#pragma unroll
        for (int q = 0; q < 4; ++q) { xv[q] = (bf16_t)x0[q]; xv[4 + q] = (bf16_t)x1[q]; }
        *(bf16x8*)&xs[0][xr * 32 + xc * 8] = xv;
    }
    __syncthreads();

    for (int t = 0; t < 32; ++t) {
        int buf = t & 1;
        bool pf = (t < 31);
        f32x4 x0, x1;
        if (pf) { // issue next-step loads early (T14)
            const float* xp = xsrc + (t + 1) * 32;
            x0 = *(const f32x4*)xp;
            x1 = *(const f32x4*)(xp + 4);
#pragma unroll
            for (int c = 0; c < 2; ++c) {
                const bf16_t* wsrc = Wt + (size_t)(nt * 128 + c * 64 + wid * 16 + (lane >> 2)) * C + (t + 1) * 32 + (lane & 3) * 8;
                __builtin_amdgcn_global_load_lds((gu32_t*)wsrc, (lu32_t*)&wt_s[buf ^ 1][c * 2048 + wid * 512], 16, 0, 0);
            }
        }
        bf16x8 a0 = *(bf16x8*)&xs[buf][(wr * 32 + lr) * 32 + lg * 8];
        bf16x8 a1 = *(bf16x8*)&xs[buf][(wr * 32 + 16 + lr) * 32 + lg * 8];
#pragma unroll
        for (int nf = 0; nf < 4; ++nf) {
            bf16x8 bb = *(bf16x8*)&wt_s[buf][(wc * 64 + nf * 16 + lr) * 32 + lg * 8];
            acc[0][nf] = MFMA(a0, bb, acc[0][nf]);
            acc[1][nf] = MFMA(a1, bb, acc[1][nf]);
        }
        if (pf) { // write-late X into next buffer
            bf16x8 xv;
#pragma unroll
            for (int q = 0; q < 4; ++q) { xv[q] = (bf16_t)x0[q]; xv[4 + q] = (bf16_t)x1[q]; }
            *(bf16x8*)&xs[buf ^ 1][xr * 32 + xc * 8] = xv;
        }
        __syncthreads();
    }
#pragma unroll
    for (int mi = 0; mi < 2; ++mi)
#pragma unroll
        for (int nf = 0; nf < 4; ++nf)
#pragma unroll
            for (int r = 0; r < 4; ++r) {
                size_t m = rw + wr * 32 + mi * 16 + lg * 4 + r;
                int d = wc * 64 + nf * 16 + lr;
                float v = acc[mi][nf][r];
                if (nt == 0)      Qb[m * D + d] = (bf16_t)v;
                else if (nt == 1) Kb[m * D + d] = (bf16_t)v;
                else              Vf[m * D + d] = v;
            }
}

// ---------------- K2: column sums l[j] (8 wave i-octants) + V scale/transpose
__global__ __launch_bounds__(512) void k_sum(const bf16_t* Qb, const bf16_t* Kb,
                                             const float* Vf, bf16_t* Vt) {
    int jt = blockIdx.x, b = blockIdx.y; // jt 0..63
    int tid = threadIdx.x;
    int lane = tid & 63, wid = tid >> 6;
    int lr = lane & 15, lg = lane >> 4;
    int j0 = jt * 32;
    __shared__ __align__(16) bf16_t vtile[128 * 32];
    __shared__ float lsum[8][32];
    __shared__ float linv[32];

    bf16x8 kf[2][4];
#pragma unroll
    for (int jh = 0; jh < 2; ++jh) {
        const bf16x8* kp = (const bf16x8*)(Kb + (size_t)(b * S + j0 + jh * 16 + lr) * D + lg * 8);
#pragma unroll
        for (int kk = 0; kk < 4; ++kk) kf[jh][kk] = kp[kk * 4];
    }
    f32x4 ls0 = {}, ls1 = {};
    for (int ii = 0; ii < 256; ii += 16) {
        int i0 = wid * 256 + ii;
        const bf16x8* qp = (const bf16x8*)(Qb + (size_t)(b * S + i0 + lr) * D + lg * 8);
        bf16x8 q0 = qp[0], q1 = qp[4], q2 = qp[8], q3 = qp[12];
        f32x4 s0 = {}, s1 = {};
        s0 = MFMA(q0, kf[0][0], s0); s0 = MFMA(q1, kf[0][1], s0);
        s0 = MFMA(q2, kf[0][2], s0); s0 = MFMA(q3, kf[0][3], s0);
        s1 = MFMA(q0, kf[1][0], s1); s1 = MFMA(q1, kf[1][1], s1);
        s1 = MFMA(q2, kf[1][2], s1); s1 = MFMA(q3, kf[1][3], s1);
#pragma unroll
        for (int r = 0; r < 4; ++r) {
            ls0[r] += exp2f(s0[r] * C2);
            ls1[r] += exp2f(s1[r] * C2);
        }
    }
    float t0 = ls0[0] + ls0[1] + ls0[2] + ls0[3];
    float t1 = ls1[0] + ls1[1] + ls1[2] + ls1[3];
    t0 += __shfl_xor(t0, 16); t0 += __shfl_xor(t0, 32);
    t1 += __shfl_xor(t1, 16); t1 += __shfl_xor(t1, 32);
    if (lane < 16) { lsum[wid][lane] = t0; lsum[wid][16 + lane] = t1; }
    __syncthreads();
    if (tid < 32) {
        float ssum = 0.f;
#pragma unroll
        for (int w = 0; w < 8; ++w) ssum += lsum[w][tid];
        linv[tid] = 1.0f / ssum;
    }
    __syncthreads();
    // scale + transpose V into Vt
#pragma unroll
    for (int p = 0; p < 2; ++p) {
        int u = p * 512 + tid;
        int jj = u >> 5, dq = u & 31;
        f32x4 v = *(const f32x4*)(Vf + (size_t)(b * S + j0 + jj) * D + dq * 4);
        float inv = linv[jj];
#pragma unroll
        for (int q = 0; q < 4; ++q) {
            int d = dq * 4 + q;
            vtile[d * 32 + (jj ^ ((d & 3) << 3))] = (bf16_t)(v[q] * inv);
        }
    }
    __syncthreads();
    {
        int u = tid;
        int d = u >> 2, jg = u & 3;
        int col0 = (jg * 8) ^ ((d & 3) << 3);
        bf16x8 row = *(const bf16x8*)&vtile[d * 32 + col0];
        *(bf16x8*)(Vt + (size_t)(b * D + d) * S + j0 + jg * 8) = row;
    }
}

// ---------------- K3: out = exp2(c*QK^T) @ Vt, 8 waves = j-eighths, 32 q-rows
__global__ __launch_bounds__(512) void k_out(const bf16_t* Qb, const bf16_t* Kb,
                                             const bf16_t* Vt, float* Out) {
    int it = blockIdx.x, b = blockIdx.y; // it 0..63
    int tid = threadIdx.x;
    int lane = tid & 63, wid = tid >> 6;
    int lr = lane & 15, lg = lane >> 4;
    int i32b = it * 32;
    __shared__ __align__(16) float sacc[16384]; // 64 KiB (bounce + reduce)
    bf16_t* pl = (bf16_t*)sacc + wid * 1024;    // 2 KiB bounce per wave

    bf16x8 qf[2][4];
#pragma unroll
    for (int ig = 0; ig < 2; ++ig) {
        const bf16x8* qp = (const bf16x8*)(Qb + (size_t)(b * S + i32b + ig * 16 + lr) * D + lg * 8);
#pragma unroll
        for (int kk = 0; kk < 4; ++kk) qf[ig][kk] = qp[kk * 4];
    }
    f32x4 acc[2][8] = {};
    const bf16_t* vb = Vt + (size_t)b * D * S;
    int jbeg = wid * 256;
    for (int j0 = jbeg; j0 < jbeg + 256; j0 += 32) {
#pragma unroll
        for (int jh = 0; jh < 2; ++jh) {
            const bf16x8* kp = (const bf16x8*)(Kb + (size_t)(b * S + j0 + jh * 16 + lr) * D + lg * 8);
            bf16x8 k0 = kp[0], k1 = kp[4], k2 = kp[8], k3 = kp[12];
#pragma unroll
            for (int ig = 0; ig < 2; ++ig) {
                f32x4 s = {};
                s = MFMA(qf[ig][0], k0, s); s = MFMA(qf[ig][1], k1, s);
                s = MFMA(qf[ig][2], k2, s); s = MFMA(qf[ig][3], k3, s);
#pragma unroll
                for (int r = 0; r < 4; ++r) {
                    int ir = lg * 4 + r;
                    pl[ig * 512 + ir * 32 + ((jh * 16 + lr) ^ ((ir & 3) << 3))] = (bf16_t)exp2f(s[r] * C2);
                }
            }
        }
        bf16x8 pa0 = *(const bf16x8*)&pl[lr * 32 + ((lg * 8) ^ ((lr & 3) << 3))];
        bf16x8 pa1 = *(const bf16x8*)&pl[512 + lr * 32 + ((lg * 8) ^ ((lr & 3) << 3))];
#pragma unroll
        for (int dc = 0; dc < 8; ++dc) {
            bf16x8 vv = *(const bf16x8*)(vb + (size_t)(dc * 16 + lr) * S + j0 + lg * 8);
            acc[0][dc] = MFMA(pa0, vv, acc[0][dc]);
            acc[1][dc] = MFMA(pa1, vv, acc[1][dc]);
        }
    }

    auto wr_region = [&](int rg) {
#pragma unroll
        for (int ig = 0; ig < 2; ++ig)
#pragma unroll
            for (int dc = 0; dc < 8; ++dc)
#pragma unroll
                for (int r = 0; r < 4; ++r)
                    sacc[rg * 4096 + (ig * 16 + lg * 4 + r) * 128 + dc * 16 + lr] = acc[ig][dc][r];
    };
    auto add_region = [&](int rg) {
#pragma unroll
        for (int ig = 0; ig < 2; ++ig)
#pragma unroll
            for (int dc = 0; dc < 8; ++dc)
#pragma unroll
                for (int r = 0; r < 4; ++r)
                    acc[ig][dc][r] += sacc[rg * 4096 + (ig * 16 + lg * 4 + r) * 128 + dc * 16 + lr];
    };

    __syncthreads(); // everyone done with bounce buffers
    if (wid >= 4) wr_region(wid - 4);
    __syncthreads();
    if (wid < 4) add_region(wid);
    __syncthreads();
    if (wid == 2 || wid == 3) wr_region(wid - 2);
    __syncthreads();
    if (wid < 2) add_region(wid);
    __syncthreads();
    if (wid == 1) wr_region(0);
    __syncthreads();
    if (wid == 0) {
        add_region(0);
#pragma unroll
        for (int ig = 0; ig < 2; ++ig)
#pragma unroll
            for (int dc = 0; dc < 8; ++dc)
#pragma unroll
                for (int r = 0; r < 4; ++r)
                    Out[(size_t)(b * S + i32b + ig * 16 + lg * 4 + r) * D + dc * 16 + lr] = acc[ig][dc][r];
    }
}

extern "C" void kernel_launch(void* const* d_in, const int* in_sizes, int n_in,
                              void* d_out, int out_size, void* d_ws, size_t ws_size,
                              hipStream_t stream) {
    const float* X  = (const float*)d_in[0];
    const float* Wq = (const float*)d_in[1];
    const float* Wk = (const float*)d_in[2];
    const float* Wv = (const float*)d_in[3];
    char* ws = (char*)d_ws;
    bf16_t* Wt = (bf16_t*)(ws);                 // 768 KiB
    bf16_t* Qb = (bf16_t*)(ws + (1ull << 20));  // 4 MiB
    bf16_t* Kb = (bf16_t*)(ws + (5ull << 20));  // 4 MiB
    float*  Vf = (float*)(ws + (9ull << 20));   // 8 MiB
    bf16_t* Vt = (bf16_t*)(ws + (17ull << 20)); // 4 MiB
    float* Out = (float*)d_out;

    k_wt<<<dim3(384), dim3(256), 0, stream>>>(Wq, Wk, Wv, Wt);
    k_qkv<<<dim3(256, 3), dim3(256), 0, stream>>>(X, Wt, Qb, Kb, Vf);
    k_sum<<<dim3(64, 8), dim3(512), 0, stream>>>(Qb, Kb, Vf, Vt);
    k_out<<<dim3(64, 8), dim3(512), 0, stream>>>(Qb, Kb, Vt, Out);
}